// Round 5
// baseline (909.689 us; speedup 1.0000x reference)
//
#include <hip/hip_runtime.h>
#include <stdint.h>

#define C 512
#define C2 262144  // 512*512

typedef __attribute__((ext_vector_type(8))) short bf16x8;
typedef __attribute__((ext_vector_type(4))) float f32x4;

__device__ __forceinline__ unsigned short f2bf(float f) {
    union { float f; uint32_t u; } v; v.f = f;
    uint32_t u = v.u;
    u += 0x7fffu + ((u >> 16) & 1u);   // round-to-nearest-even
    return (unsigned short)(u >> 16);
}
__device__ __forceinline__ float bf2f(unsigned short h) {
    union { uint32_t u; float f; } v; v.u = ((uint32_t)h) << 16;
    return v.f;
}

#define GL2LDS16(g, l) __builtin_amdgcn_global_load_lds( \
    (const __attribute__((address_space(1))) void*)(g),  \
    (__attribute__((address_space(3))) void*)(l), 16, 0, 0)

__device__ __forceinline__ int nth_valid(int mask, int n) {
    int pq = 0;
    while (true) {
        if (mask & 1) { if (n == 0) return pq; --n; }
        mask >>= 1; ++pq;
    }
}

// K [o][i][3][3] fp32 ->
//   Kt  bf16 [j][o][c] = K[o][c][j]   (GEMM B operand)
//   KtT bf16 [j][i][c] = K[c][i][j]   (step-2 GEMM A operand = Ki1^T)
//   Ktf f32  [j][i][o] = K[o][i][j]   (assembly K-term, coalesced in o)
__global__ void k_transform(const float* __restrict__ K,
                            unsigned short* __restrict__ Kt,
                            unsigned short* __restrict__ KtT,
                            float* __restrict__ Ktf) {
    int t = blockIdx.x * 256 + threadIdx.x;  // t = a*512 + b
    int a = t >> 9, b = t & 511;
#pragma unroll
    for (int j = 0; j < 9; ++j) {
        float v = K[(size_t)t * 9 + j];
        unsigned short h = f2bf(v);
        Kt[(size_t)j * C2 + t] = h;
        KtT[(size_t)j * C2 + (size_t)b * C + a] = h;
        Ktf[(size_t)j * C2 + (size_t)b * C + a] = v;
    }
}

// Build heavy-first work lists + zero counters.
// sched layout: int ctr[4]; then 4 lists of 484 ints (stride 484).
__global__ void k_sched(int* __restrict__ sched) {
    int tid = threadIdx.x;
    if (tid < 4) sched[tid] = 0;
    if (tid < 4) {
        const int s_out = 5 + 2 * tid;
        const int s_in = s_out - 2;
        const int s2 = s_out * s_out;
        int* list = sched + 4 + tid * 484;
        int pos = 0;
        for (int v = 9; v >= 1; --v) {
            for (int yx = 0; yx < s2; ++yx) {
                int y = yx / s_out, x = yx % s_out;
                int vy = 0, vx = 0;
                for (int p = 0; p < 3; ++p) {
                    if (y - p >= 0 && y - p < s_in) ++vy;
                    if (x - p >= 0 && x - p < s_in) ++vx;
                }
                if (vy * vx == v) {
                    list[pos++] = yx * 4 + 0;
                    list[pos++] = yx * 4 + 1;
                    list[pos++] = yx * 4 + 2;
                    list[pos++] = yx * 4 + 3;
                }
            }
        }
    }
}

// Persistent-block 256x256-tile 8-phase MFMA GEMM with work-stealing.
// Ki_t^T[yx][i][o] = alpha * sum_{pq valid} sum_c A[uv][i][c] * B[pq][o][c]
// LDS ring: slots {0,1}=B par0, {2,3}=A par0, {4,5}=B par1, {6,7}=A par1,
// slot 8 = dump for tail prefetches. Restages at ph1/ph3/ph5/ph7 (one phase
// AFTER each slot-pair's last read), vmcnt(4) at end-ph2/end-ph6.
__global__ __launch_bounds__(512, 2) void k_gemm(
    const unsigned short* __restrict__ A,   // [s_in^2][512 i][512 c] bf16
    const unsigned short* __restrict__ Bm,  // [9][512 o][512 c] bf16
    unsigned short* __restrict__ Out,       // [s_out^2][512 i][512 o] bf16
    int s_in, int s_out, float alpha,
    int* __restrict__ ctr, const int* __restrict__ list, int n_items)
{
    __shared__ __align__(16) char lds[147456];
    __shared__ int s_item;

    const int tid = threadIdx.x;
    const int lane = tid & 63, wid = tid >> 6;
    const int wr = wid >> 2, wc = wid & 3;        // 2(M) x 4(N) waves
    const int l15 = lane & 15, lhi = lane >> 4;

    // staging: thread covers source rows tid>>3 (+64/+128/+192), col
    // pre-swizzled so linear LDS dest + XOR read = consistent involution
    const int srow = tid >> 3, scol = tid & 7;
    const int soff0 = srow * 1024 + ((scol ^ (srow & 7)) * 16);
    const int soff1 = soff0 + 65536;       // +64 rows: (row&7) unchanged
    const int t16 = tid * 16;

    // fragment-read constants (swizzled)
    const int swz = (l15 & 7) << 4;
    const int coff0 = (lhi * 16) ^ swz;          // kk=0
    const int coff1 = (64 + lhi * 16) ^ swz;     // kk=1
    const int bbase = ((wc >> 1) * 16384) + ((wc & 1) * 64 + l15) * 128;
    const int abase = 32768 + wr * 16384 + l15 * 128;

    const char* Abase = (const char*)A;
    const char* Bbase = (const char*)Bm;

    for (;;) {
        __syncthreads();                       // prev item fully done w/ LDS
        if (tid == 0) s_item = atomicAdd(ctr, 1);
        __syncthreads();
        const int itm = s_item;
        if (itm >= n_items) break;
        const int code = list[itm];
        const int yx = code >> 2, quad = code & 3;
        const int i0 = (quad & 1) * 256, o0 = (quad >> 1) * 256;
        const int y = yx / s_out, x = yx % s_out;

        int mask = 0, V = 0;
        for (int pq = 0; pq < 9; ++pq) {
            int u = y - pq / 3, v = x - pq % 3;
            if (u >= 0 && u < s_in && v >= 0 && v < s_in) { mask |= 1 << pq; ++V; }
        }

        auto slabA = [&](int pq) {
            int u = y - pq / 3, v = x - pq % 3;
            return Abase + ((size_t)(u * s_in + v) * C + i0) * (size_t)(C * 2);
        };
        auto slabB = [&](int pq) {
            return Bbase + ((size_t)pq * C + o0) * (size_t)(C * 2);
        };
        const int pq0 = nth_valid(mask, 0);
        const char* curA = slabA(pq0);
        const char* curB = slabB(pq0);
        const char* nxtA = curA;
        const char* nxtB = curB;
        if (V > 1) { int p1 = nth_valid(mask, 1); nxtA = slabA(p1); nxtB = slabB(p1); }

        f32x4 acc[8][4] = {};
        bf16x8 bB[8];
        bf16x8 aReg[2][4];

        // ---- prologue: K-step 0 -> par0 slots, K-step 1 -> par1 slots ----
        {
            GL2LDS16(curB + soff0,          lds + t16);
            GL2LDS16(curB + soff1,          lds + 8192 + t16);
            GL2LDS16(curB + 131072 + soff0, lds + 16384 + t16);
            GL2LDS16(curB + 131072 + soff1, lds + 16384 + 8192 + t16);
            GL2LDS16(curA + soff0,          lds + 32768 + t16);
            GL2LDS16(curA + soff1,          lds + 32768 + 8192 + t16);
            GL2LDS16(curA + 131072 + soff0, lds + 49152 + t16);
            GL2LDS16(curA + 131072 + soff1, lds + 49152 + 8192 + t16);
            GL2LDS16(curB + 128 + soff0,          lds + 65536 + t16);
            GL2LDS16(curB + 128 + soff1,          lds + 65536 + 8192 + t16);
            GL2LDS16(curB + 128 + 131072 + soff0, lds + 81920 + t16);
            GL2LDS16(curB + 128 + 131072 + soff1, lds + 81920 + 8192 + t16);
            GL2LDS16(curA + 128 + soff0,          lds + 98304 + t16);
            GL2LDS16(curA + 128 + soff1,          lds + 98304 + 8192 + t16);
            GL2LDS16(curA + 128 + 131072 + soff0, lds + 114688 + t16);
            GL2LDS16(curA + 128 + 131072 + soff1, lds + 114688 + 8192 + t16);
        }
        // stale tail dummies (<=12) + 16 new: vmcnt(8) drains all stale + par0
        asm volatile("s_waitcnt vmcnt(8)" ::: "memory");
        __builtin_amdgcn_s_barrier();
#pragma unroll
        for (int mi = 0; mi < 2; ++mi) {              // preload A-quad0 par0
            aReg[0][mi * 2 + 0] = *(const bf16x8*)(lds + abase + mi * 2048 + coff0);
            aReg[0][mi * 2 + 1] = *(const bf16x8*)(lds + abase + mi * 2048 + coff1);
        }

#define STAGEPAIR(SRC, DSTOFF) { \
        const char* s0_ = (SRC); \
        char* d0_ = dummy ? (lds + 131072) : (lds + (DSTOFF)); \
        char* d1_ = dummy ? (lds + 131072) : (lds + (DSTOFF) + 16384); \
        GL2LDS16(s0_ + soff0,          d0_ + t16); \
        GL2LDS16(s0_ + soff1,          d0_ + 8192 + t16); \
        GL2LDS16(s0_ + 131072 + soff0, d1_ + t16); \
        GL2LDS16(s0_ + 131072 + soff1, d1_ + 8192 + t16); \
    }

        const int NI = 4 * V;
        for (int it = 0; it < NI; ++it) {
            const bool lastq = ((it & 3) == 3);
            const bool dummy = lastq && (((it >> 2) + 1) >= V);
            const char* sAe = lastq ? nxtA : curA;
            const char* sBe = lastq ? nxtB : curB;
            const int cse = lastq ? 0 : (2 * (it & 3) + 2) * 128;  // K-step 2it+2
            const int cso = cse + 128;                              // K-step 2it+3

#define PHASE(PH) { \
        constexpr int g_ = (PH) & 3, par_ = (PH) >> 2; \
        constexpr int cur_ = (PH) & 1, nxt_ = cur_ ^ 1; \
        constexpr int qn_ = (g_ + 1) & 3; \
        constexpr int pn_ = (g_ == 3) ? (par_ ^ 1) : par_; \
        if constexpr (g_ == 0) { \
            _Pragma("unroll") for (int n = 0; n < 4; ++n) { \
                bB[n * 2 + 0] = *(const bf16x8*)(lds + par_ * 65536 + bbase + n * 2048 + coff0); \
                bB[n * 2 + 1] = *(const bf16x8*)(lds + par_ * 65536 + bbase + n * 2048 + coff1); \
            } \
        } \
        _Pragma("unroll") for (int mi = 0; mi < 2; ++mi) { \
            aReg[nxt_][mi * 2 + 0] = *(const bf16x8*)(lds + pn_ * 65536 + abase + qn_ * 4096 + mi * 2048 + coff0); \
            aReg[nxt_][mi * 2 + 1] = *(const bf16x8*)(lds + pn_ * 65536 + abase + qn_ * 4096 + mi * 2048 + coff1); \
        } \
        asm volatile("" ::: "memory"); \
        if constexpr ((PH) == 1) STAGEPAIR(sBe + cse, 0)       /* B par0 */ \
        if constexpr ((PH) == 3) STAGEPAIR(sAe + cse, 32768)   /* A par0 */ \
        if constexpr ((PH) == 5) STAGEPAIR(sBe + cso, 65536)   /* B par1 */ \
        if constexpr ((PH) == 7) STAGEPAIR(sAe + cso, 98304)   /* A par1 */ \
        __builtin_amdgcn_s_barrier(); \
        asm volatile("s_waitcnt lgkmcnt(0)" ::: "memory"); \
        __builtin_amdgcn_sched_barrier(0); \
        __builtin_amdgcn_s_setprio(1); \
        _Pragma("unroll") for (int mi = 0; mi < 2; ++mi) \
        _Pragma("unroll") for (int n = 0; n < 4; ++n) { \
            acc[g_ * 2 + mi][n] = __builtin_amdgcn_mfma_f32_16x16x32_bf16( \
                aReg[cur_][mi * 2 + 0], bB[n * 2 + 0], acc[g_ * 2 + mi][n], 0, 0, 0); \
            acc[g_ * 2 + mi][n] = __builtin_amdgcn_mfma_f32_16x16x32_bf16( \
                aReg[cur_][mi * 2 + 1], bB[n * 2 + 1], acc[g_ * 2 + mi][n], 0, 0, 0); \
        } \
        __builtin_amdgcn_s_setprio(0); \
        if constexpr ((PH) == 2 || (PH) == 6) { \
            asm volatile("s_waitcnt vmcnt(4)" ::: "memory"); \
        } \
        __builtin_amdgcn_s_barrier(); \
        __builtin_amdgcn_sched_barrier(0); \
    }

            PHASE(0) PHASE(1) PHASE(2) PHASE(3)
            PHASE(4) PHASE(5) PHASE(6) PHASE(7)
#undef PHASE

            if (lastq) {
                curA = nxtA; curB = nxtB;
                int vn = (it >> 2) + 2;
                if (vn < V) {
                    int pqn = nth_valid(mask, vn);
                    nxtA = slabA(pqn); nxtB = slabB(pqn);
                }
            }
        }
#undef STAGEPAIR

        // D layout per 16x16 frag: col(o)=lane&15, row(i)=(lane>>4)*4+reg
#pragma unroll
        for (int M = 0; M < 8; ++M) {
#pragma unroll
            for (int r = 0; r < 4; ++r) {
                const int irow = i0 + wr * 128 + M * 16 + lhi * 4 + r;
                unsigned short* op = Out + ((size_t)yx * C + irow) * C
                                   + o0 + wc * 64 + l15;
#pragma unroll
                for (int n = 0; n < 4; ++n)
                    op[n * 16] = f2bf(acc[M][n][r] * alpha);
            }
        }
    }
    asm volatile("s_waitcnt vmcnt(0)" ::: "memory");  // drain tail dummies
}

// Fused assembly: kg[o][i][11][11] (+)= centered Ka + centered Kb
// init=1: plain store, also adds K-term + identity (no kg pre-read).
__global__ __launch_bounds__(256) void k_final(
    const unsigned short* __restrict__ Ka, int sa, int ofa,
    const unsigned short* __restrict__ Kb, int sb, int ofb,
    const float* __restrict__ Ktf, float* __restrict__ kg, int init)
{
    __shared__ float L[64 * 121];
    const int i = blockIdx.x;
    const int o0 = blockIdx.y * 64;
    const int tid = threadIdx.x, lane = tid & 63, wid = tid >> 6;

    for (int idx = tid; idx < 64 * 121; idx += 256) L[idx] = 0.f;
    __syncthreads();

    const int sa2 = sa * sa;
    for (int yxv = wid; yxv < sa2; yxv += 4) {
        float v = bf2f(Ka[((size_t)yxv * C + i) * C + o0 + lane]);
        int yy = yxv / sa + ofa, xx = yxv % sa + ofa;
        L[lane * 121 + yy * 11 + xx] += v;   // lane owns o_local, yx distinct
    }
    __syncthreads();
    const int sb2 = sb * sb;
    for (int yxv = wid; yxv < sb2; yxv += 4) {
        float v = bf2f(Kb[((size_t)yxv * C + i) * C + o0 + lane]);
        int yy = yxv / sb + ofb, xx = yxv % sb + ofb;
        L[lane * 121 + yy * 11 + xx] += v;
    }
    __syncthreads();
    if (init) {
        for (int j = wid; j < 9; j += 4) {
            float v = Ktf[(size_t)j * C2 + (size_t)i * C + o0 + lane];
            if (j == 4 && (o0 + lane) == i) v += 1.0f;  // identity at (5,5)
            L[lane * 121 + (j / 3 + 4) * 11 + (j % 3 + 4)] += v;
        }
    }
    __syncthreads();
    if (init) {
        for (int idx = tid; idx < 64 * 121; idx += 256) {
            int ol = idx / 121, w = idx - ol * 121;
            kg[((size_t)(o0 + ol) * C + i) * 121 + w] = L[idx];
        }
    } else {
        for (int idx = tid; idx < 64 * 121; idx += 256) {
            int ol = idx / 121, w = idx - ol * 121;
            kg[((size_t)(o0 + ol) * C + i) * 121 + w] += L[idx];
        }
    }
}

extern "C" void kernel_launch(void* const* d_in, const int* in_sizes, int n_in,
                              void* d_out, int out_size, void* d_ws, size_t ws_size,
                              hipStream_t stream) {
    const float* K = (const float*)d_in[0];
    float* kg = (float*)d_out;
    char* ws = (char*)d_ws;

    // ws: Kt 4.5MB | KtT 4.5MB | Ktf 9MB | P1 42.5MB (Ki2,Ki4) | P2 63.5MB
    // (Ki3,Ki5) | sched 8KB (4 counters + 4 heavy-first item lists)
    unsigned short* Kt  = (unsigned short*)(ws);
    unsigned short* KtT = (unsigned short*)(ws + (size_t)4718592);
    float*          Ktf = (float*)         (ws + (size_t)9437184);
    unsigned short* P1  = (unsigned short*)(ws + (size_t)18874368);
    unsigned short* P2  = (unsigned short*)(ws + (size_t)61341696);
    int*            sch = (int*)           (ws + (size_t)124780544);
    int* ctr = sch;            // 4 counters
    int* lst = sch + 4;        // 4 lists, stride 484 ints

    k_transform<<<1024, 256, 0, stream>>>(K, Kt, KtT, Ktf);
    k_sched<<<1, 64, 0, stream>>>(sch);

    // t=2: Ki2^T = (K*K)/2          A=KtT(3x3) -> P1 (5x5)
    k_gemm<<<256, 512, 0, stream>>>(KtT, Kt, P1, 3, 5, 0.5f,
                                    ctr + 0, lst + 0 * 484, 100);
    // t=3: Ki3^T = (K*Ki2)/3        A=P1 (5x5) -> P2 (7x7)
    k_gemm<<<256, 512, 0, stream>>>(P1, Kt, P2, 5, 7, 1.0f / 3.0f,
                                    ctr + 1, lst + 1 * 484, 196);
    // assembly pass 1: kg = K-term + I + Ki2@3 + Ki3@2
    k_final<<<dim3(512, 8), 256, 0, stream>>>(P1, 5, 3, P2, 7, 2, Ktf, kg, 1);
    // t=4: Ki4^T = (K*Ki3)/4        A=P2 (7x7) -> P1 (9x9)
    k_gemm<<<256, 512, 0, stream>>>(P2, Kt, P1, 7, 9, 0.25f,
                                    ctr + 2, lst + 2 * 484, 324);
    // t=5: Ki5^T = (K*Ki4)/5        A=P1 (9x9) -> P2 (11x11)
    k_gemm<<<256, 512, 0, stream>>>(P1, Kt, P2, 9, 11, 0.2f,
                                    ctr + 3, lst + 3 * 484, 484);
    // assembly pass 2: kg += Ki4@1 + Ki5@0
    k_final<<<dim3(512, 8), 256, 0, stream>>>(P1, 9, 1, P2, 11, 0, Ktf, kg, 0);
}

// Round 6
// 899.097 us; speedup vs baseline: 1.0118x; 1.0118x over previous
//
#include <hip/hip_runtime.h>
#include <stdint.h>

#define C 512
#define C2 262144  // 512*512

typedef __attribute__((ext_vector_type(8))) short bf16x8;
typedef __attribute__((ext_vector_type(4))) float f32x4;

__device__ __forceinline__ unsigned short f2bf(float f) {
    union { float f; uint32_t u; } v; v.f = f;
    uint32_t u = v.u;
    u += 0x7fffu + ((u >> 16) & 1u);   // round-to-nearest-even
    return (unsigned short)(u >> 16);
}
__device__ __forceinline__ float bf2f(unsigned short h) {
    union { uint32_t u; float f; } v; v.u = ((uint32_t)h) << 16;
    return v.f;
}

#define GL2LDS16(g, l) __builtin_amdgcn_global_load_lds( \
    (const __attribute__((address_space(1))) void*)(g),  \
    (__attribute__((address_space(3))) void*)(l), 16, 0, 0)

// Inline-asm LDS read: invisible to hipcc's alias analysis, so the compiler
// cannot insert its own vmcnt drains before it (the round-5 per-phase stall).
// Ordering vs global_load_lds is enforced ONLY by our counted vmcnt/barriers.
__device__ __forceinline__ bf16x8 ldsr16(const char* p) {
    bf16x8 r;
    asm volatile("ds_read_b128 %0, %1"
                 : "=v"(r)
                 : "v"((__attribute__((address_space(3))) const void*)p));
    return r;
}

__device__ __forceinline__ int nth_valid(int mask, int n) {
    int pq = 0;
    while (true) {
        if (mask & 1) { if (n == 0) return pq; --n; }
        mask >>= 1; ++pq;
    }
}

// K [o][i][3][3] fp32 ->
//   Kt  bf16 [j][o][c] = K[o][c][j]   (GEMM B operand)
//   KtT bf16 [j][i][c] = K[c][i][j]   (step-2 GEMM A operand = Ki1^T)
//   Ktf f32  [j][i][o] = K[o][i][j]   (assembly K-term, coalesced in o)
__global__ void k_transform(const float* __restrict__ K,
                            unsigned short* __restrict__ Kt,
                            unsigned short* __restrict__ KtT,
                            float* __restrict__ Ktf) {
    int t = blockIdx.x * 256 + threadIdx.x;  // t = a*512 + b
    int a = t >> 9, b = t & 511;
#pragma unroll
    for (int j = 0; j < 9; ++j) {
        float v = K[(size_t)t * 9 + j];
        unsigned short h = f2bf(v);
        Kt[(size_t)j * C2 + t] = h;
        KtT[(size_t)j * C2 + (size_t)b * C + a] = h;
        Ktf[(size_t)j * C2 + (size_t)b * C + a] = v;
    }
}

// Build heavy-first work lists + zero counters.
// sched layout: int ctr[4]; then 4 lists of 484 ints (stride 484).
__global__ void k_sched(int* __restrict__ sched) {
    int tid = threadIdx.x;
    if (tid < 4) sched[tid] = 0;
    if (tid < 4) {
        const int s_out = 5 + 2 * tid;
        const int s_in = s_out - 2;
        const int s2 = s_out * s_out;
        int* list = sched + 4 + tid * 484;
        int pos = 0;
        for (int v = 9; v >= 1; --v) {
            for (int yx = 0; yx < s2; ++yx) {
                int y = yx / s_out, x = yx % s_out;
                int vy = 0, vx = 0;
                for (int p = 0; p < 3; ++p) {
                    if (y - p >= 0 && y - p < s_in) ++vy;
                    if (x - p >= 0 && x - p < s_in) ++vx;
                }
                if (vy * vx == v) {
                    list[pos++] = yx * 4 + 0;
                    list[pos++] = yx * 4 + 1;
                    list[pos++] = yx * 4 + 2;
                    list[pos++] = yx * 4 + 3;
                }
            }
        }
    }
}

// Persistent-block 256x256-tile 8-phase MFMA GEMM with work-stealing.
// Ki_t^T[yx][i][o] = alpha * sum_{pq valid} sum_c A[uv][i][c] * B[pq][o][c]
// LDS ring: slots {0,1}=B par0, {2,3}=A par0, {4,5}=B par1, {6,7}=A par1,
// slot 8 = dump for tail prefetches. Restages at ph1/ph3/ph5/ph7 (one phase
// AFTER each slot-pair's last read), vmcnt(4) at end-ph2/end-ph6.
__global__ __launch_bounds__(512, 2) void k_gemm(
    const unsigned short* __restrict__ A,   // [s_in^2][512 i][512 c] bf16
    const unsigned short* __restrict__ Bm,  // [9][512 o][512 c] bf16
    unsigned short* __restrict__ Out,       // [s_out^2][512 i][512 o] bf16
    int s_in, int s_out, float alpha,
    int* __restrict__ ctr, const int* __restrict__ list, int n_items)
{
    __shared__ __align__(16) char lds[147456];
    __shared__ int s_item;

    const int tid = threadIdx.x;
    const int lane = tid & 63, wid = tid >> 6;
    const int wr = wid >> 2, wc = wid & 3;        // 2(M) x 4(N) waves
    const int l15 = lane & 15, lhi = lane >> 4;

    // staging: thread covers source rows tid>>3 (+64/+128/+192), col
    // pre-swizzled so linear LDS dest + XOR read = consistent involution
    const int srow = tid >> 3, scol = tid & 7;
    const int soff0 = srow * 1024 + ((scol ^ (srow & 7)) * 16);
    const int soff1 = soff0 + 65536;       // +64 rows: (row&7) unchanged
    const int t16 = tid * 16;

    // fragment-read constants (swizzled)
    const int swz = (l15 & 7) << 4;
    const int coff0 = (lhi * 16) ^ swz;          // kk=0
    const int coff1 = (64 + lhi * 16) ^ swz;     // kk=1
    const int bbase = ((wc >> 1) * 16384) + ((wc & 1) * 64 + l15) * 128;
    const int abase = 32768 + wr * 16384 + l15 * 128;

    const char* Abase = (const char*)A;
    const char* Bbase = (const char*)Bm;

    for (;;) {
        __syncthreads();                       // prev item fully done w/ LDS
        if (tid == 0) s_item = atomicAdd(ctr, 1);
        __syncthreads();
        const int itm = s_item;
        if (itm >= n_items) break;
        const int code = list[itm];
        const int yx = code >> 2, quad = code & 3;
        const int i0 = (quad & 1) * 256, o0 = (quad >> 1) * 256;
        const int y = yx / s_out, x = yx % s_out;

        int mask = 0, V = 0;
        for (int pq = 0; pq < 9; ++pq) {
            int u = y - pq / 3, v = x - pq % 3;
            if (u >= 0 && u < s_in && v >= 0 && v < s_in) { mask |= 1 << pq; ++V; }
        }

        auto slabA = [&](int pq) {
            int u = y - pq / 3, v = x - pq % 3;
            return Abase + ((size_t)(u * s_in + v) * C + i0) * (size_t)(C * 2);
        };
        auto slabB = [&](int pq) {
            return Bbase + ((size_t)pq * C + o0) * (size_t)(C * 2);
        };
        const int pq0 = nth_valid(mask, 0);
        const char* curA = slabA(pq0);
        const char* curB = slabB(pq0);
        const char* nxtA = curA;
        const char* nxtB = curB;
        if (V > 1) { int p1 = nth_valid(mask, 1); nxtA = slabA(p1); nxtB = slabB(p1); }

        f32x4 acc[8][4] = {};
        bf16x8 bB[8];
        bf16x8 aReg[2][4];

        // ---- prologue: K-step 0 -> par0 slots, K-step 1 -> par1 slots ----
        {
            GL2LDS16(curB + soff0,          lds + t16);
            GL2LDS16(curB + soff1,          lds + 8192 + t16);
            GL2LDS16(curB + 131072 + soff0, lds + 16384 + t16);
            GL2LDS16(curB + 131072 + soff1, lds + 16384 + 8192 + t16);
            GL2LDS16(curA + soff0,          lds + 32768 + t16);
            GL2LDS16(curA + soff1,          lds + 32768 + 8192 + t16);
            GL2LDS16(curA + 131072 + soff0, lds + 49152 + t16);
            GL2LDS16(curA + 131072 + soff1, lds + 49152 + 8192 + t16);
            GL2LDS16(curB + 128 + soff0,          lds + 65536 + t16);
            GL2LDS16(curB + 128 + soff1,          lds + 65536 + 8192 + t16);
            GL2LDS16(curB + 128 + 131072 + soff0, lds + 81920 + t16);
            GL2LDS16(curB + 128 + 131072 + soff1, lds + 81920 + 8192 + t16);
            GL2LDS16(curA + 128 + soff0,          lds + 98304 + t16);
            GL2LDS16(curA + 128 + soff1,          lds + 98304 + 8192 + t16);
            GL2LDS16(curA + 128 + 131072 + soff0, lds + 114688 + t16);
            GL2LDS16(curA + 128 + 131072 + soff1, lds + 114688 + 8192 + t16);
        }
        // stale tail dummies (<=12) + 16 new: vmcnt(8) drains all stale + par0
        asm volatile("s_waitcnt vmcnt(8)" ::: "memory");
        __builtin_amdgcn_s_barrier();
        __builtin_amdgcn_sched_barrier(0);
#pragma unroll
        for (int mi = 0; mi < 2; ++mi) {              // preload A-quad0 par0
            aReg[0][mi * 2 + 0] = ldsr16(lds + abase + mi * 2048 + coff0);
            aReg[0][mi * 2 + 1] = ldsr16(lds + abase + mi * 2048 + coff1);
        }

#define STAGEPAIR(SRC, DSTOFF) { \
        const char* s0_ = (SRC); \
        char* d0_ = dummy ? (lds + 131072) : (lds + (DSTOFF)); \
        char* d1_ = dummy ? (lds + 131072) : (lds + (DSTOFF) + 16384); \
        GL2LDS16(s0_ + soff0,          d0_ + t16); \
        GL2LDS16(s0_ + soff1,          d0_ + 8192 + t16); \
        GL2LDS16(s0_ + 131072 + soff0, d1_ + t16); \
        GL2LDS16(s0_ + 131072 + soff1, d1_ + 8192 + t16); \
    }

        const int NI = 4 * V;
        for (int it = 0; it < NI; ++it) {
            const bool lastq = ((it & 3) == 3);
            const bool dummy = lastq && (((it >> 2) + 1) >= V);
            const char* sAe = lastq ? nxtA : curA;
            const char* sBe = lastq ? nxtB : curB;
            const int cse = lastq ? 0 : (2 * (it & 3) + 2) * 128;  // K-step 2it+2
            const int cso = cse + 128;                              // K-step 2it+3

#define PHASE(PH) { \
        constexpr int g_ = (PH) & 3, par_ = (PH) >> 2; \
        constexpr int cur_ = (PH) & 1, nxt_ = cur_ ^ 1; \
        constexpr int qn_ = (g_ + 1) & 3; \
        constexpr int pn_ = (g_ == 3) ? (par_ ^ 1) : par_; \
        if constexpr (g_ == 0) { \
            _Pragma("unroll") for (int n = 0; n < 4; ++n) { \
                bB[n * 2 + 0] = ldsr16(lds + par_ * 65536 + bbase + n * 2048 + coff0); \
                bB[n * 2 + 1] = ldsr16(lds + par_ * 65536 + bbase + n * 2048 + coff1); \
            } \
        } \
        _Pragma("unroll") for (int mi = 0; mi < 2; ++mi) { \
            aReg[nxt_][mi * 2 + 0] = ldsr16(lds + pn_ * 65536 + abase + qn_ * 4096 + mi * 2048 + coff0); \
            aReg[nxt_][mi * 2 + 1] = ldsr16(lds + pn_ * 65536 + abase + qn_ * 4096 + mi * 2048 + coff1); \
        } \
        asm volatile("" ::: "memory"); \
        if constexpr ((PH) == 1) STAGEPAIR(sBe + cse, 0)       /* B par0 */ \
        if constexpr ((PH) == 3) STAGEPAIR(sAe + cse, 32768)   /* A par0 */ \
        if constexpr ((PH) == 5) STAGEPAIR(sBe + cso, 65536)   /* B par1 */ \
        if constexpr ((PH) == 7) STAGEPAIR(sAe + cso, 98304)   /* A par1 */ \
        __builtin_amdgcn_s_barrier(); \
        asm volatile("s_waitcnt lgkmcnt(0)" ::: "memory"); \
        __builtin_amdgcn_sched_barrier(0); \
        __builtin_amdgcn_s_setprio(1); \
        _Pragma("unroll") for (int mi = 0; mi < 2; ++mi) \
        _Pragma("unroll") for (int n = 0; n < 4; ++n) { \
            acc[g_ * 2 + mi][n] = __builtin_amdgcn_mfma_f32_16x16x32_bf16( \
                aReg[cur_][mi * 2 + 0], bB[n * 2 + 0], acc[g_ * 2 + mi][n], 0, 0, 0); \
            acc[g_ * 2 + mi][n] = __builtin_amdgcn_mfma_f32_16x16x32_bf16( \
                aReg[cur_][mi * 2 + 1], bB[n * 2 + 1], acc[g_ * 2 + mi][n], 0, 0, 0); \
        } \
        __builtin_amdgcn_s_setprio(0); \
        if constexpr ((PH) == 2 || (PH) == 6) { \
            asm volatile("s_waitcnt vmcnt(4)" ::: "memory"); \
        } \
        __builtin_amdgcn_s_barrier(); \
        __builtin_amdgcn_sched_barrier(0); \
    }

            PHASE(0) PHASE(1) PHASE(2) PHASE(3)
            PHASE(4) PHASE(5) PHASE(6) PHASE(7)
#undef PHASE

            if (lastq) {
                curA = nxtA; curB = nxtB;
                int vn = (it >> 2) + 2;
                if (vn < V) {
                    int pqn = nth_valid(mask, vn);
                    nxtA = slabA(pqn); nxtB = slabB(pqn);
                }
            }
        }
#undef STAGEPAIR

        // D layout per 16x16 frag: col(o)=lane&15, row(i)=(lane>>4)*4+reg
#pragma unroll
        for (int M = 0; M < 8; ++M) {
#pragma unroll
            for (int r = 0; r < 4; ++r) {
                const int irow = i0 + wr * 128 + M * 16 + lhi * 4 + r;
                unsigned short* op = Out + ((size_t)yx * C + irow) * C
                                   + o0 + wc * 64 + l15;
#pragma unroll
                for (int n = 0; n < 4; ++n)
                    op[n * 16] = f2bf(acc[M][n][r] * alpha);
            }
        }
    }
    asm volatile("s_waitcnt vmcnt(0)" ::: "memory");  // drain tail dummies
}

// Fused assembly: kg[o][i][11][11] (+)= centered Ka + centered Kb
// init=1: plain store, also adds K-term + identity (no kg pre-read).
__global__ __launch_bounds__(256) void k_final(
    const unsigned short* __restrict__ Ka, int sa, int ofa,
    const unsigned short* __restrict__ Kb, int sb, int ofb,
    const float* __restrict__ Ktf, float* __restrict__ kg, int init)
{
    __shared__ float L[64 * 121];
    const int i = blockIdx.x;
    const int o0 = blockIdx.y * 64;
    const int tid = threadIdx.x, lane = tid & 63, wid = tid >> 6;

    for (int idx = tid; idx < 64 * 121; idx += 256) L[idx] = 0.f;
    __syncthreads();

    const int sa2 = sa * sa;
    for (int yxv = wid; yxv < sa2; yxv += 4) {
        float v = bf2f(Ka[((size_t)yxv * C + i) * C + o0 + lane]);
        int yy = yxv / sa + ofa, xx = yxv % sa + ofa;
        L[lane * 121 + yy * 11 + xx] += v;   // lane owns o_local, yx distinct
    }
    __syncthreads();
    const int sb2 = sb * sb;
    for (int yxv = wid; yxv < sb2; yxv += 4) {
        float v = bf2f(Kb[((size_t)yxv * C + i) * C + o0 + lane]);
        int yy = yxv / sb + ofb, xx = yxv % sb + ofb;
        L[lane * 121 + yy * 11 + xx] += v;
    }
    __syncthreads();
    if (init) {
        for (int j = wid; j < 9; j += 4) {
            float v = Ktf[(size_t)j * C2 + (size_t)i * C + o0 + lane];
            if (j == 4 && (o0 + lane) == i) v += 1.0f;  // identity at (5,5)
            L[lane * 121 + (j / 3 + 4) * 11 + (j % 3 + 4)] += v;
        }
    }
    __syncthreads();
    if (init) {
        for (int idx = tid; idx < 64 * 121; idx += 256) {
            int ol = idx / 121, w = idx - ol * 121;
            kg[((size_t)(o0 + ol) * C + i) * 121 + w] = L[idx];
        }
    } else {
        for (int idx = tid; idx < 64 * 121; idx += 256) {
            int ol = idx / 121, w = idx - ol * 121;
            kg[((size_t)(o0 + ol) * C + i) * 121 + w] += L[idx];
        }
    }
}

extern "C" void kernel_launch(void* const* d_in, const int* in_sizes, int n_in,
                              void* d_out, int out_size, void* d_ws, size_t ws_size,
                              hipStream_t stream) {
    const float* K = (const float*)d_in[0];
    float* kg = (float*)d_out;
    char* ws = (char*)d_ws;

    // ws: Kt 4.5MB | KtT 4.5MB | Ktf 9MB | P1 42.5MB (Ki2,Ki4) | P2 63.5MB
    // (Ki3,Ki5) | sched 8KB (4 counters + 4 heavy-first item lists)
    unsigned short* Kt  = (unsigned short*)(ws);
    unsigned short* KtT = (unsigned short*)(ws + (size_t)4718592);
    float*          Ktf = (float*)         (ws + (size_t)9437184);
    unsigned short* P1  = (unsigned short*)(ws + (size_t)18874368);
    unsigned short* P2  = (unsigned short*)(ws + (size_t)61341696);
    int*            sch = (int*)           (ws + (size_t)124780544);
    int* ctr = sch;            // 4 counters
    int* lst = sch + 4;        // 4 lists, stride 484 ints

    k_transform<<<1024, 256, 0, stream>>>(K, Kt, KtT, Ktf);
    k_sched<<<1, 64, 0, stream>>>(sch);

    // t=2: Ki2^T = (K*K)/2          A=KtT(3x3) -> P1 (5x5)
    k_gemm<<<256, 512, 0, stream>>>(KtT, Kt, P1, 3, 5, 0.5f,
                                    ctr + 0, lst + 0 * 484, 100);
    // t=3: Ki3^T = (K*Ki2)/3        A=P1 (5x5) -> P2 (7x7)
    k_gemm<<<256, 512, 0, stream>>>(P1, Kt, P2, 5, 7, 1.0f / 3.0f,
                                    ctr + 1, lst + 1 * 484, 196);
    // assembly pass 1: kg = K-term + I + Ki2@3 + Ki3@2
    k_final<<<dim3(512, 8), 256, 0, stream>>>(P1, 5, 3, P2, 7, 2, Ktf, kg, 1);
    // t=4: Ki4^T = (K*Ki3)/4        A=P2 (7x7) -> P1 (9x9)
    k_gemm<<<256, 512, 0, stream>>>(P2, Kt, P1, 7, 9, 0.25f,
                                    ctr + 2, lst + 2 * 484, 324);
    // t=5: Ki5^T = (K*Ki4)/5        A=P1 (9x9) -> P2 (11x11)
    k_gemm<<<256, 512, 0, stream>>>(P1, Kt, P2, 9, 11, 0.2f,
                                    ctr + 3, lst + 3 * 484, 484);
    // assembly pass 2: kg += Ki4@1 + Ki5@0
    k_final<<<dim3(512, 8), 256, 0, stream>>>(P1, 9, 1, P2, 11, 0, Ktf, kg, 0);
}

// Round 7
// 661.160 us; speedup vs baseline: 1.3759x; 1.3599x over previous
//
#include <hip/hip_runtime.h>
#include <stdint.h>

#define C 512
#define C2 262144  // 512*512

typedef __attribute__((ext_vector_type(8))) short bf16x8;
typedef __attribute__((ext_vector_type(4))) float f32x4;

__device__ __forceinline__ unsigned short f2bf(float f) {
    union { float f; uint32_t u; } v; v.f = f;
    uint32_t u = v.u;
    u += 0x7fffu + ((u >> 16) & 1u);   // round-to-nearest-even
    return (unsigned short)(u >> 16);
}
__device__ __forceinline__ float bf2f(unsigned short h) {
    union { uint32_t u; float f; } v; v.u = ((uint32_t)h) << 16;
    return v.f;
}

#define GL2LDS16(g, l) __builtin_amdgcn_global_load_lds( \
    (const __attribute__((address_space(1))) void*)(g),  \
    (__attribute__((address_space(3))) void*)(l), 16, 0, 0)

__device__ __forceinline__ bf16x8 ldsr16(const char* p) {
    bf16x8 r;
    asm volatile("ds_read_b128 %0, %1"
                 : "=v"(r)
                 : "v"((__attribute__((address_space(3))) const void*)p));
    return r;
}

__device__ __forceinline__ int nth_valid(int mask, int n) {
    int pq = 0;
    while (true) {
        if (mask & 1) { if (n == 0) return pq; --n; }
        mask >>= 1; ++pq;
    }
}

// K [o][i][3][3] fp32 ->
//   Kt  bf16 [j][o][c] = K[o][c][j]   (GEMM B operand)
//   KtT bf16 [j][i][c] = K[c][i][j]   (step-2 GEMM A operand = Ki1^T)
//   Ktf f32  [j][i][o] = K[o][i][j]   (assembly K-term, coalesced in o)
__global__ void k_transform(const float* __restrict__ K,
                            unsigned short* __restrict__ Kt,
                            unsigned short* __restrict__ KtT,
                            float* __restrict__ Ktf) {
    int t = blockIdx.x * 256 + threadIdx.x;  // t = a*512 + b
    int a = t >> 9, b = t & 511;
#pragma unroll
    for (int j = 0; j < 9; ++j) {
        float v = K[(size_t)t * 9 + j];
        unsigned short h = f2bf(v);
        Kt[(size_t)j * C2 + t] = h;
        KtT[(size_t)j * C2 + (size_t)b * C + a] = h;
        Ktf[(size_t)j * C2 + (size_t)b * C + a] = v;
    }
}

// Parallel heavy-first work-list build + counter zeroing.
// Thread t -> (step, yx). LDS histogram over V-classes, prefix (heavy first),
// atomic slot within class (intra-class order irrelevant: output is
// order-independent). sched: int ctr[4]; 4 lists of 484 ints (stride 484).
__global__ void k_sched(int* __restrict__ sched) {
    __shared__ int hist[4][10];
    __shared__ int base[4][10];
    const int tid = threadIdx.x;
    if (tid < 40) ((int*)hist)[tid] = 0;
    if (tid < 4) sched[tid] = 0;
    __syncthreads();
    const int offs[5] = {0, 25, 74, 155, 276};
    int step = -1, yx = 0, V = 0;
    if (tid < 276) {
#pragma unroll
        for (int s = 0; s < 4; ++s)
            if (tid >= offs[s] && tid < offs[s + 1]) { step = s; yx = tid - offs[s]; }
        const int s_out = 5 + 2 * step, s_in = s_out - 2;
        const int y = yx / s_out, x = yx % s_out;
        int vy = 0, vx = 0;
#pragma unroll
        for (int p = 0; p < 3; ++p) {
            if (y - p >= 0 && y - p < s_in) ++vy;
            if (x - p >= 0 && x - p < s_in) ++vx;
        }
        V = vy * vx;
        atomicAdd(&hist[step][V], 1);
    }
    __syncthreads();
    if (tid < 4) {
        int acc = 0;
        for (int v = 9; v >= 1; --v) { base[tid][v] = acc; acc += hist[tid][v]; }
        for (int v = 1; v <= 9; ++v) hist[tid][v] = 0;   // reuse as cursor
    }
    __syncthreads();
    if (tid < 276) {
        const int idx = atomicAdd(&hist[step][V], 1);
        const int slot = base[step][V] + idx;
        int* list = sched + 4 + step * 484;
        list[slot * 4 + 0] = yx * 4 + 0;
        list[slot * 4 + 1] = yx * 4 + 1;
        list[slot * 4 + 2] = yx * 4 + 2;
        list[slot * 4 + 3] = yx * 4 + 3;
    }
}

// Persistent-block 256x256-tile 8-phase MFMA GEMM with work-stealing.
// Ki_t^T[yx][i][o] = alpha * sum_{pq valid} sum_c A[uv][i][c] * B[pq][o][c]
// LDS ring: slots {0,1}=B par0, {2,3}=A par0, {4,5}=B par1, {6,7}=A par1,
// slot 8 = dump for tail prefetches. Restages at ph1/ph3/ph5/ph7 (one phase
// AFTER each slot-pair's last read), vmcnt(4) at end-ph2/end-ph6.
// lgkmcnt(4) per phase: leaves ONLY this phase's 4 A-prefetch reads in
// flight (DS completes in order) -> prefetch is finally asynchronous.
__global__ __launch_bounds__(512, 2) void k_gemm(
    const unsigned short* __restrict__ A,   // [s_in^2][512 i][512 c] bf16
    const unsigned short* __restrict__ Bm,  // [9][512 o][512 c] bf16
    unsigned short* __restrict__ Out,       // [s_out^2][512 i][512 o] bf16
    int s_in, int s_out, float alpha,
    int* __restrict__ ctr, const int* __restrict__ list, int n_items)
{
    __shared__ __align__(16) char lds[147456];
    __shared__ int s_item;

    const int tid = threadIdx.x;
    const int lane = tid & 63, wid = tid >> 6;
    const int wr = wid >> 2, wc = wid & 3;        // 2(M) x 4(N) waves
    const int l15 = lane & 15, lhi = lane >> 4;

    const int srow = tid >> 3, scol = tid & 7;
    const int soff0 = srow * 1024 + ((scol ^ (srow & 7)) * 16);
    const int soff1 = soff0 + 65536;       // +64 rows: (row&7) unchanged
    const int t16 = tid * 16;

    const int swz = (l15 & 7) << 4;
    const int coff0 = (lhi * 16) ^ swz;          // kk=0
    const int coff1 = (64 + lhi * 16) ^ swz;     // kk=1
    const int bbase = ((wc >> 1) * 16384) + ((wc & 1) * 64 + l15) * 128;
    const int abase = 32768 + wr * 16384 + l15 * 128;

    const char* Abase = (const char*)A;
    const char* Bbase = (const char*)Bm;

    for (;;) {
        __syncthreads();                       // prev item fully done w/ LDS
        if (tid == 0) s_item = atomicAdd(ctr, 1);
        __syncthreads();
        const int itm = s_item;
        if (itm >= n_items) break;
        const int code = list[itm];
        const int yx = code >> 2, quad = code & 3;
        const int i0 = (quad & 1) * 256, o0 = (quad >> 1) * 256;
        const int y = yx / s_out, x = yx % s_out;

        int mask = 0, V = 0;
        for (int pq = 0; pq < 9; ++pq) {
            int u = y - pq / 3, v = x - pq % 3;
            if (u >= 0 && u < s_in && v >= 0 && v < s_in) { mask |= 1 << pq; ++V; }
        }

        auto slabA = [&](int pq) {
            int u = y - pq / 3, v = x - pq % 3;
            return Abase + ((size_t)(u * s_in + v) * C + i0) * (size_t)(C * 2);
        };
        auto slabB = [&](int pq) {
            return Bbase + ((size_t)pq * C + o0) * (size_t)(C * 2);
        };
        const int pq0 = nth_valid(mask, 0);
        const char* curA = slabA(pq0);
        const char* curB = slabB(pq0);
        const char* nxtA = curA;
        const char* nxtB = curB;
        if (V > 1) { int p1 = nth_valid(mask, 1); nxtA = slabA(p1); nxtB = slabB(p1); }

        f32x4 acc[8][4] = {};
        bf16x8 bB[8];
        bf16x8 aReg[2][4];

        // ---- prologue: K-step 0 -> par0 slots, K-step 1 -> par1 slots ----
        {
            GL2LDS16(curB + soff0,          lds + t16);
            GL2LDS16(curB + soff1,          lds + 8192 + t16);
            GL2LDS16(curB + 131072 + soff0, lds + 16384 + t16);
            GL2LDS16(curB + 131072 + soff1, lds + 16384 + 8192 + t16);
            GL2LDS16(curA + soff0,          lds + 32768 + t16);
            GL2LDS16(curA + soff1,          lds + 32768 + 8192 + t16);
            GL2LDS16(curA + 131072 + soff0, lds + 49152 + t16);
            GL2LDS16(curA + 131072 + soff1, lds + 49152 + 8192 + t16);
            GL2LDS16(curB + 128 + soff0,          lds + 65536 + t16);
            GL2LDS16(curB + 128 + soff1,          lds + 65536 + 8192 + t16);
            GL2LDS16(curB + 128 + 131072 + soff0, lds + 81920 + t16);
            GL2LDS16(curB + 128 + 131072 + soff1, lds + 81920 + 8192 + t16);
            GL2LDS16(curA + 128 + soff0,          lds + 98304 + t16);
            GL2LDS16(curA + 128 + soff1,          lds + 98304 + 8192 + t16);
            GL2LDS16(curA + 128 + 131072 + soff0, lds + 114688 + t16);
            GL2LDS16(curA + 128 + 131072 + soff1, lds + 114688 + 8192 + t16);
        }
        asm volatile("s_waitcnt vmcnt(8)" ::: "memory");
        __builtin_amdgcn_s_barrier();
        __builtin_amdgcn_sched_barrier(0);
#pragma unroll
        for (int mi = 0; mi < 2; ++mi) {              // preload A-quad0 par0
            aReg[0][mi * 2 + 0] = ldsr16(lds + abase + mi * 2048 + coff0);
            aReg[0][mi * 2 + 1] = ldsr16(lds + abase + mi * 2048 + coff1);
        }

#define STAGEPAIR(SRC, DSTOFF) { \
        const char* s0_ = (SRC); \
        char* d0_ = dummy ? (lds + 131072) : (lds + (DSTOFF)); \
        char* d1_ = dummy ? (lds + 131072) : (lds + (DSTOFF) + 16384); \
        GL2LDS16(s0_ + soff0,          d0_ + t16); \
        GL2LDS16(s0_ + soff1,          d0_ + 8192 + t16); \
        GL2LDS16(s0_ + 131072 + soff0, d1_ + t16); \
        GL2LDS16(s0_ + 131072 + soff1, d1_ + 8192 + t16); \
    }

        const int NI = 4 * V;
        for (int it = 0; it < NI; ++it) {
            const bool lastq = ((it & 3) == 3);
            const bool dummy = lastq && (((it >> 2) + 1) >= V);
            const char* sAe = lastq ? nxtA : curA;
            const char* sBe = lastq ? nxtB : curB;
            const int cse = lastq ? 0 : (2 * (it & 3) + 2) * 128;  // K-step 2it+2
            const int cso = cse + 128;                              // K-step 2it+3

#define PHASE(PH) { \
        constexpr int g_ = (PH) & 3, par_ = (PH) >> 2; \
        constexpr int cur_ = (PH) & 1, nxt_ = cur_ ^ 1; \
        constexpr int qn_ = (g_ + 1) & 3; \
        constexpr int pn_ = (g_ == 3) ? (par_ ^ 1) : par_; \
        if constexpr (g_ == 0) { \
            _Pragma("unroll") for (int n = 0; n < 4; ++n) { \
                bB[n * 2 + 0] = ldsr16(lds + par_ * 65536 + bbase + n * 2048 + coff0); \
                bB[n * 2 + 1] = ldsr16(lds + par_ * 65536 + bbase + n * 2048 + coff1); \
            } \
        } \
        _Pragma("unroll") for (int mi = 0; mi < 2; ++mi) { \
            aReg[nxt_][mi * 2 + 0] = ldsr16(lds + pn_ * 65536 + abase + qn_ * 4096 + mi * 2048 + coff0); \
            aReg[nxt_][mi * 2 + 1] = ldsr16(lds + pn_ * 65536 + abase + qn_ * 4096 + mi * 2048 + coff1); \
        } \
        asm volatile("" ::: "memory"); \
        if constexpr ((PH) == 1) STAGEPAIR(sBe + cse, 0)       /* B par0 */ \
        if constexpr ((PH) == 3) STAGEPAIR(sAe + cse, 32768)   /* A par0 */ \
        if constexpr ((PH) == 5) STAGEPAIR(sBe + cso, 65536)   /* B par1 */ \
        if constexpr ((PH) == 7) STAGEPAIR(sAe + cso, 98304)   /* A par1 */ \
        __builtin_amdgcn_s_barrier(); \
        asm volatile("s_waitcnt lgkmcnt(4)" ::: "memory"); \
        __builtin_amdgcn_sched_barrier(0); \
        __builtin_amdgcn_s_setprio(1); \
        _Pragma("unroll") for (int mi = 0; mi < 2; ++mi) \
        _Pragma("unroll") for (int n = 0; n < 4; ++n) { \
            acc[g_ * 2 + mi][n] = __builtin_amdgcn_mfma_f32_16x16x32_bf16( \
                aReg[cur_][mi * 2 + 0], bB[n * 2 + 0], acc[g_ * 2 + mi][n], 0, 0, 0); \
            acc[g_ * 2 + mi][n] = __builtin_amdgcn_mfma_f32_16x16x32_bf16( \
                aReg[cur_][mi * 2 + 1], bB[n * 2 + 1], acc[g_ * 2 + mi][n], 0, 0, 0); \
        } \
        __builtin_amdgcn_s_setprio(0); \
        if constexpr ((PH) == 2 || (PH) == 6) { \
            asm volatile("s_waitcnt vmcnt(4)" ::: "memory"); \
        } \
        __builtin_amdgcn_s_barrier(); \
        __builtin_amdgcn_sched_barrier(0); \
    }

            PHASE(0) PHASE(1) PHASE(2) PHASE(3)
            PHASE(4) PHASE(5) PHASE(6) PHASE(7)
#undef PHASE

            if (lastq) {
                curA = nxtA; curB = nxtB;
                int vn = (it >> 2) + 2;
                if (vn < V) {
                    int pqn = nth_valid(mask, vn);
                    nxtA = slabA(pqn); nxtB = slabB(pqn);
                }
            }
        }
#undef STAGEPAIR

        // D layout per 16x16 frag: col(o)=lane&15, row(i)=(lane>>4)*4+reg
#pragma unroll
        for (int M = 0; M < 8; ++M) {
#pragma unroll
            for (int r = 0; r < 4; ++r) {
                const int irow = i0 + wr * 128 + M * 16 + lhi * 4 + r;
                unsigned short* op = Out + ((size_t)yx * C + irow) * C
                                   + o0 + wc * 64 + l15;
#pragma unroll
                for (int n = 0; n < 4; ++n)
                    op[n * 16] = f2bf(acc[M][n][r] * alpha);
            }
        }
    }
    asm volatile("s_waitcnt vmcnt(0)" ::: "memory");  // drain tail dummies
}

// Two-source assembly (fallback path), identical to round 6.
__global__ __launch_bounds__(256) void k_final(
    const unsigned short* __restrict__ Ka, int sa, int ofa,
    const unsigned short* __restrict__ Kb, int sb, int ofb,
    const float* __restrict__ Ktf, float* __restrict__ kg, int init)
{
    __shared__ float L[64 * 121];
    const int i = blockIdx.x;
    const int o0 = blockIdx.y * 64;
    const int tid = threadIdx.x, lane = tid & 63, wid = tid >> 6;

    for (int idx = tid; idx < 64 * 121; idx += 256) L[idx] = 0.f;
    __syncthreads();

    const int sa2 = sa * sa;
    for (int yxv = wid; yxv < sa2; yxv += 4) {
        float v = bf2f(Ka[((size_t)yxv * C + i) * C + o0 + lane]);
        int yy = yxv / sa + ofa, xx = yxv % sa + ofa;
        L[lane * 121 + yy * 11 + xx] += v;
    }
    __syncthreads();
    const int sb2 = sb * sb;
    for (int yxv = wid; yxv < sb2; yxv += 4) {
        float v = bf2f(Kb[((size_t)yxv * C + i) * C + o0 + lane]);
        int yy = yxv / sb + ofb, xx = yxv % sb + ofb;
        L[lane * 121 + yy * 11 + xx] += v;
    }
    __syncthreads();
    if (init) {
        for (int j = wid; j < 9; j += 4) {
            float v = Ktf[(size_t)j * C2 + (size_t)i * C + o0 + lane];
            if (j == 4 && (o0 + lane) == i) v += 1.0f;
            L[lane * 121 + (j / 3 + 4) * 11 + (j % 3 + 4)] += v;
        }
    }
    __syncthreads();
    if (init) {
        for (int idx = tid; idx < 64 * 121; idx += 256) {
            int ol = idx / 121, w = idx - ol * 121;
            kg[((size_t)(o0 + ol) * C + i) * 121 + w] = L[idx];
        }
    } else {
        for (int idx = tid; idx < 64 * 121; idx += 256) {
            int ol = idx / 121, w = idx - ol * 121;
            kg[((size_t)(o0 + ol) * C + i) * 121 + w] += L[idx];
        }
    }
}

// Fused four-source assembly (big-ws path): kg = I + K + Ki2..Ki5, one pass,
// plain stores (no RMW).
__global__ __launch_bounds__(256) void k_final4(
    const unsigned short* __restrict__ K2, const unsigned short* __restrict__ K3,
    const unsigned short* __restrict__ K4, const unsigned short* __restrict__ K5,
    const float* __restrict__ Ktf, float* __restrict__ kg)
{
    __shared__ float L[64 * 121];
    const int i = blockIdx.x;
    const int o0 = blockIdx.y * 64;
    const int tid = threadIdx.x, lane = tid & 63, wid = tid >> 6;

    for (int idx = tid; idx < 64 * 121; idx += 256) L[idx] = 0.f;
    __syncthreads();

#define ADDSRC(SRC, S, OFS) { \
        const int s2_ = (S) * (S); \
        for (int yxv = wid; yxv < s2_; yxv += 4) { \
            float v = bf2f((SRC)[((size_t)yxv * C + i) * C + o0 + lane]); \
            int yy = yxv / (S) + (OFS), xx = yxv % (S) + (OFS); \
            L[lane * 121 + yy * 11 + xx] += v; \
        } \
        __syncthreads(); \
    }
    ADDSRC(K2, 5, 3) ADDSRC(K3, 7, 2) ADDSRC(K4, 9, 1) ADDSRC(K5, 11, 0)
#undef ADDSRC

    for (int j = wid; j < 9; j += 4) {
        float v = Ktf[(size_t)j * C2 + (size_t)i * C + o0 + lane];
        if (j == 4 && (o0 + lane) == i) v += 1.0f;   // identity at (5,5)
        L[lane * 121 + (j / 3 + 4) * 11 + (j % 3 + 4)] += v;
    }
    __syncthreads();
    for (int idx = tid; idx < 64 * 121; idx += 256) {
        int ol = idx / 121, w = idx - ol * 121;
        kg[((size_t)(o0 + ol) * C + i) * 121 + w] = L[idx];
    }
}

extern "C" void kernel_launch(void* const* d_in, const int* in_sizes, int n_in,
                              void* d_out, int out_size, void* d_ws, size_t ws_size,
                              hipStream_t stream) {
    const float* K = (const float*)d_in[0];
    float* kg = (float*)d_out;
    char* ws = (char*)d_ws;

    unsigned short* Kt  = (unsigned short*)(ws);
    unsigned short* KtT = (unsigned short*)(ws + (size_t)4718592);
    float*          Ktf = (float*)         (ws + (size_t)9437184);

    const bool big = (ws_size >= (size_t)163585616);

    if (big) {
        // Ki2@18874368(13MB) Ki3@31981568(25.7MB) Ki4@57671680(42.5MB)
        // Ki5@100139008(63.4MB) sched@163577856(7760B)
        unsigned short* Ki2 = (unsigned short*)(ws + (size_t)18874368);
        unsigned short* Ki3 = (unsigned short*)(ws + (size_t)31981568);
        unsigned short* Ki4 = (unsigned short*)(ws + (size_t)57671680);
        unsigned short* Ki5 = (unsigned short*)(ws + (size_t)100139008);
        int* sch = (int*)(ws + (size_t)163577856);
        int* ctr = sch;
        int* lst = sch + 4;

        k_transform<<<1024, 256, 0, stream>>>(K, Kt, KtT, Ktf);
        k_sched<<<1, 320, 0, stream>>>(sch);
        k_gemm<<<256, 512, 0, stream>>>(KtT, Kt, Ki2, 3, 5, 0.5f,
                                        ctr + 0, lst + 0 * 484, 100);
        k_gemm<<<256, 512, 0, stream>>>(Ki2, Kt, Ki3, 5, 7, 1.0f / 3.0f,
                                        ctr + 1, lst + 1 * 484, 196);
        k_gemm<<<256, 512, 0, stream>>>(Ki3, Kt, Ki4, 7, 9, 0.25f,
                                        ctr + 2, lst + 2 * 484, 324);
        k_gemm<<<256, 512, 0, stream>>>(Ki4, Kt, Ki5, 9, 11, 0.2f,
                                        ctr + 3, lst + 3 * 484, 484);
        k_final4<<<dim3(512, 8), 256, 0, stream>>>(Ki2, Ki3, Ki4, Ki5, Ktf, kg);
    } else {
        // P1 42.5MB (Ki2,Ki4) | P2 63.5MB (Ki3,Ki5) | sched 8KB
        unsigned short* P1 = (unsigned short*)(ws + (size_t)18874368);
        unsigned short* P2 = (unsigned short*)(ws + (size_t)61341696);
        int* sch = (int*)(ws + (size_t)124780544);
        int* ctr = sch;
        int* lst = sch + 4;

        k_transform<<<1024, 256, 0, stream>>>(K, Kt, KtT, Ktf);
        k_sched<<<1, 320, 0, stream>>>(sch);
        k_gemm<<<256, 512, 0, stream>>>(KtT, Kt, P1, 3, 5, 0.5f,
                                        ctr + 0, lst + 0 * 484, 100);
        k_gemm<<<256, 512, 0, stream>>>(P1, Kt, P2, 5, 7, 1.0f / 3.0f,
                                        ctr + 1, lst + 1 * 484, 196);
        k_final<<<dim3(512, 8), 256, 0, stream>>>(P1, 5, 3, P2, 7, 2, Ktf, kg, 1);
        k_gemm<<<256, 512, 0, stream>>>(P2, Kt, P1, 7, 9, 0.25f,
                                        ctr + 2, lst + 2 * 484, 324);
        k_gemm<<<256, 512, 0, stream>>>(P1, Kt, P2, 9, 11, 0.2f,
                                        ctr + 3, lst + 3 * 484, 484);
        k_final<<<dim3(512, 8), 256, 0, stream>>>(P1, 9, 1, P2, 11, 0, Ktf, kg, 0);
    }
}